// Round 2
// baseline (245.993 us; speedup 1.0000x reference)
//
#include <hip/hip_runtime.h>
#include <hip/hip_bf16.h>

#define INPUT_DIM 2048
#define EMBED_DIM 128
#define NROWS 16384

typedef __bf16 bf16x8 __attribute__((ext_vector_type(8)));
typedef float f32x4 __attribute__((ext_vector_type(4)));

__device__ inline float dot4(f32x4 a, f32x4 b) {
    return a.x * b.x + a.y * b.y + a.z * b.z + a.w * b.w;
}

// ---- prep: Vt[n][k] = (bf16)V[k][n]  (128x2048 bf16), s[k] = sum_n V[k][n]^2
__global__ __launch_bounds__(256) void fm_prep(const float* __restrict__ V,
                                               __bf16* __restrict__ Vt,
                                               float* __restrict__ s) {
    const int bid = blockIdx.x;
    const int tid = threadIdx.x;
    if (bid < 128) {
        const int g = bid * 256 + tid;   // 0..32767
        const int n = g & 127;
        const int kc = g >> 7;           // 0..255 (8-wide k chunks)
        bf16x8 o;
#pragma unroll
        for (int e = 0; e < 8; ++e)
            o[e] = (__bf16)V[(kc * 8 + e) * EMBED_DIM + n];
        *(bf16x8*)(Vt + (size_t)n * INPUT_DIM + kc * 8) = o;
    } else {
        const int k = (bid - 128) * 256 + tid;  // 0..2047
        const f32x4* row = (const f32x4*)(V + (size_t)k * EMBED_DIM);
        float acc = 0.f;
#pragma unroll
        for (int j = 0; j < EMBED_DIM / 4; ++j) {
            f32x4 v = row[j];
            acc += dot4(v, v);
        }
        s[k] = acc;
    }
}

// ---- main: per block = 16 rows, 4 waves K-split (512 k each).
// Wave: A-frag direct from global x (fp32->bf16 in regs), B-frag from Vt.
// acc[c] covers n = c*16..c*16+16 for rows row0..row0+16.
// LDS pad 128->132: partial-tile store goes 4-way -> 2-way bank aliasing (free, m136).
__global__ __launch_bounds__(256, 4) void fm_main(const float* __restrict__ x,
                                                  const float* __restrict__ W,
                                                  const float* __restrict__ bptr,
                                                  const __bf16* __restrict__ Vt,
                                                  const float* __restrict__ s,
                                                  float* __restrict__ out) {
    __shared__ __align__(16) float acc_lds[4][16][132];
    __shared__ float lin_lds[4][16];
    __shared__ float sq_lds[4][16];

    const int tid = threadIdx.x;
    const int w = tid >> 6;     // wave id: k-split index
    const int l = tid & 63;
    const int lr = l & 15;      // A row / B col within 16
    const int lg = l >> 4;      // k-group within fragment

    const int row0 = blockIdx.x * 16;
    const int k0 = w * 512;

    const float* xp = x + (size_t)(row0 + lr) * INPUT_DIM + k0 + lg * 8;
    const float* wp = W + k0 + lg * 8;
    const float* sp = s + k0 + lg * 8;
    const __bf16* vtp = Vt + (size_t)lr * INPUT_DIM + k0 + lg * 8;

    f32x4 acc[8];
#pragma unroll
    for (int c = 0; c < 8; ++c) acc[c] = (f32x4){0.f, 0.f, 0.f, 0.f};
    float lin = 0.f, sq = 0.f;

    for (int step = 0; step < 16; ++step) {
        f32x4 a0 = *(const f32x4*)xp;
        f32x4 a1 = *(const f32x4*)(xp + 4);
        f32x4 w0 = *(const f32x4*)wp;
        f32x4 w1 = *(const f32x4*)(wp + 4);
        f32x4 s0 = *(const f32x4*)sp;
        f32x4 s1 = *(const f32x4*)(sp + 4);
        xp += 32; wp += 32; sp += 32;

        lin += dot4(a0, w0) + dot4(a1, w1);
        sq += dot4(a0 * a0, s0) + dot4(a1 * a1, s1);

        bf16x8 af;
        af[0] = (__bf16)a0.x; af[1] = (__bf16)a0.y;
        af[2] = (__bf16)a0.z; af[3] = (__bf16)a0.w;
        af[4] = (__bf16)a1.x; af[5] = (__bf16)a1.y;
        af[6] = (__bf16)a1.z; af[7] = (__bf16)a1.w;

#pragma unroll
        for (int c = 0; c < 8; ++c) {
            bf16x8 bf = *(const bf16x8*)(vtp + (size_t)c * 16 * INPUT_DIM);
            acc[c] = __builtin_amdgcn_mfma_f32_16x16x32_bf16(af, bf, acc[c], 0, 0, 0);
        }
        vtp += 32;
    }

    // stash partial xv tiles: C/D layout (m89): col = l&15, row = (l>>4)*4 + r
#pragma unroll
    for (int c = 0; c < 8; ++c)
#pragma unroll
        for (int r = 0; r < 4; ++r)
            acc_lds[w][lg * 4 + r][c * 16 + lr] = acc[c][r];

    // fold lin/sq over the 4 k-groups (lanes differing in lg)
    lin += __shfl_xor(lin, 16); lin += __shfl_xor(lin, 32);
    sq  += __shfl_xor(sq, 16);  sq  += __shfl_xor(sq, 32);
    if (l < 16) { lin_lds[w][l] = lin; sq_lds[w][l] = sq; }
    __syncthreads();

    // combine K-split partials, then square & reduce over n
    {
        const int row = tid >> 4;        // 0..15, 16 consecutive lanes per row
        const int nc = (tid & 15) * 8;
        f32x4 v0 = (f32x4){0.f, 0.f, 0.f, 0.f};
        f32x4 v1 = (f32x4){0.f, 0.f, 0.f, 0.f};
#pragma unroll
        for (int ww = 0; ww < 4; ++ww) {
            v0 += *(const f32x4*)&acc_lds[ww][row][nc];
            v1 += *(const f32x4*)&acc_lds[ww][row][nc + 4];
        }
        float ss = dot4(v0, v0) + dot4(v1, v1);
        ss += __shfl_xor(ss, 1);
        ss += __shfl_xor(ss, 2);
        ss += __shfl_xor(ss, 4);
        ss += __shfl_xor(ss, 8);
        if ((tid & 15) == 0) {
            float linf = lin_lds[0][row] + lin_lds[1][row] + lin_lds[2][row] + lin_lds[3][row];
            float sqf  = sq_lds[0][row] + sq_lds[1][row] + sq_lds[2][row] + sq_lds[3][row];
            out[row0 + row] = linf + bptr[0] + 0.5f * (ss - sqf);
        }
    }
}

extern "C" void kernel_launch(void* const* d_in, const int* in_sizes, int n_in,
                              void* d_out, int out_size, void* d_ws, size_t ws_size,
                              hipStream_t stream) {
    const float* x = (const float*)d_in[0];
    const float* W = (const float*)d_in[1];
    const float* b = (const float*)d_in[2];
    const float* V = (const float*)d_in[3];
    float* out = (float*)d_out;

    __bf16* Vt = (__bf16*)d_ws;                                     // 128*2048*2 = 512 KB
    float* s = (float*)((char*)d_ws + 128 * 2048 * sizeof(__bf16)); // 8 KB

    fm_prep<<<136, 256, 0, stream>>>(V, Vt, s);
    fm_main<<<1024, 256, 0, stream>>>(x, W, b, Vt, s, out);
}